// Round 1
// 263.851 us; speedup vs baseline: 1.1153x; 1.1153x over previous
//
#include <hip/hip_runtime.h>
#include <stdint.h>

typedef int v4i  __attribute__((ext_vector_type(4)));
typedef int v16i __attribute__((ext_vector_type(16)));

#define DIN 1024
#define QMAXF 127.0f

// Weight quant + swizzle into MFMA-fragment-coalesced layout.
// 16B chunk (n, k16) -> BqS 16B-slot [((n>>5)*32 + (k16>>1))*64 + (n&31) + 32*(k16&1)]
// so a wave's K-loop fragment load is ONE contiguous 1KB segment (lane i at +16*i).
__global__ __launch_bounds__(256) void quant_w(
    const float* __restrict__ w, char* __restrict__ wq,
    float* __restrict__ wscale)
{
    int wave = threadIdx.x >> 6;
    int lane = threadIdx.x & 63;
    int r = blockIdx.x * 4 + wave;

    const float* src = w + (size_t)r * DIN;

    // lane holds 16 contiguous floats -> 16 contiguous int8 (k16 chunk = lane)
    float4 v[4];
    #pragma unroll
    for (int j = 0; j < 4; j++)
        v[j] = ((const float4*)src)[lane * 4 + j];

    float a = 0.0f;
    #pragma unroll
    for (int j = 0; j < 4; j++)
        a = fmaxf(a, fmaxf(fmaxf(fabsf(v[j].x), fabsf(v[j].y)),
                           fmaxf(fabsf(v[j].z), fabsf(v[j].w))));
    #pragma unroll
    for (int off = 32; off; off >>= 1)
        a = fmaxf(a, __shfl_xor(a, off));
    a = fmaxf(a, 1e-8f);

    float inv = QMAXF / a;
    int pk[4];
    #pragma unroll
    for (int j = 0; j < 4; j++) {
        int q0 = max(-128, min(127, __float2int_rn(v[j].x * inv)));
        int q1 = max(-128, min(127, __float2int_rn(v[j].y * inv)));
        int q2 = max(-128, min(127, __float2int_rn(v[j].z * inv)));
        int q3 = max(-128, min(127, __float2int_rn(v[j].w * inv)));
        pk[j] = (int)((unsigned)(q0 & 255) | ((unsigned)(q1 & 255) << 8) |
                      ((unsigned)(q2 & 255) << 16) | ((unsigned)(q3 & 255) << 24));
    }
    v4i pkv = { pk[0], pk[1], pk[2], pk[3] };

    int nb  = r >> 5;                       // 32-row n-block
    int ks  = lane >> 1;                    // k16 = lane ; ks = k16>>1
    int sub = (r & 31) + 32 * (lane & 1);   // frag lane slot
    ((v4i*)wq)[(size_t)(nb * 32 + ks) * 64 + sub] = pkv;

    if (lane == 0) wscale[r] = a / QMAXF;
}

// Fused per-token quant + int8 GEMM. Block = 64 token rows x full N=1024,
// 1024 threads = 16 waves. Quant phase: coalesced x reads (lane-stride 16B),
// pack 4B per j, ds_write_b32 into XOR-chunk-swizzled As (LDS row r chunk c
// holds data chunk c^(r&7)); row scale in LDS. K-loop: A from LDS with
// explicit 1-iter register prefetch; B from the fragment-order BqS layout --
// each load is a contiguous 1KB wave segment (fully coalesced, L2-hot) with
// 1-iter register double-buffer.
__global__ __launch_bounds__(1024) void gemm_i8_fused(
    const float* __restrict__ x, const char* __restrict__ Bq,
    const float* __restrict__ wscale, const float* __restrict__ bias,
    float* __restrict__ out, int N)
{
    __shared__ char As[64 * 1024];
    __shared__ float xs_lds[64];

    int m0 = blockIdx.x * 64;
    int w = threadIdx.x >> 6;
    int lane = threadIdx.x & 63;

    // ---- fused quant phase: 4 rows per wave, coalesced reads ----
    for (int i = 0; i < 4; i++) {
        int r = w * 4 + i;
        const float* src = x + (size_t)(m0 + r) * DIN;
        float4 v[4];
        #pragma unroll
        for (int j = 0; j < 4; j++)
            v[j] = ((const float4*)src)[lane + 64 * j];   // lane-stride 16B

        float a = 0.0f;
        #pragma unroll
        for (int j = 0; j < 4; j++)
            a = fmaxf(a, fmaxf(fmaxf(fabsf(v[j].x), fabsf(v[j].y)),
                               fmaxf(fabsf(v[j].z), fabsf(v[j].w))));
        #pragma unroll
        for (int off = 32; off; off >>= 1)
            a = fmaxf(a, __shfl_xor(a, off));
        a = fmaxf(a, 1e-8f);

        float inv = QMAXF / a;
        #pragma unroll
        for (int j = 0; j < 4; j++) {
            int q0 = max(-128, min(127, __float2int_rn(v[j].x * inv)));
            int q1 = max(-128, min(127, __float2int_rn(v[j].y * inv)));
            int q2 = max(-128, min(127, __float2int_rn(v[j].z * inv)));
            int q3 = max(-128, min(127, __float2int_rn(v[j].w * inv)));
            unsigned pk = (unsigned)(q0 & 255) | ((unsigned)(q1 & 255) << 8) |
                          ((unsigned)(q2 & 255) << 16) | ((unsigned)(q3 & 255) << 24);
            // dword index in row = lane + 64*j ; 16B chunk c = (lane>>2)+16*j
            int c = (lane >> 2) + 16 * j;
            *(unsigned*)(As + r * 1024 + ((c ^ (r & 7)) << 4) + (lane & 3) * 4) = pk;
        }
        if (lane == 0) xs_lds[r] = a / QMAXF;
    }
    __syncthreads();

    // ---- K loop ----
    int frow = lane & 31;
    int sel  = lane >> 5;          // K half: kh = sel*16
    int wn   = w * 64;
    int xork = frow & 7;

    // fragment-order B: wave w slab starts at n-block 2w; lane i at +16*i.
    const char* bp = Bq + ((size_t)(w * 2) * 2048 + (size_t)lane) * 16;
    const char* As0 = As + frow * 1024;
    const char* As1 = As + (frow + 32) * 1024;

    v16i acc00 = {}; v16i acc01 = {}; v16i acc10 = {}; v16i acc11 = {};

    v4i b0c = *(const v4i*)(bp);
    v4i b1c = *(const v4i*)(bp + 32768);
    int c0 = (sel ^ xork) << 4;
    v4i a0c = *(const v4i*)(As0 + c0);
    v4i a1c = *(const v4i*)(As1 + c0);

    #pragma unroll 4
    for (int ks = 0; ks < 32; ks++) {
        v4i a0n, a1n, b0n, b1n;
        if (ks < 31) {
            const char* bn = bp + (ks + 1) * 1024;
            b0n = *(const v4i*)(bn);
            b1n = *(const v4i*)(bn + 32768);
            int cn = ((2 * (ks + 1) + sel) ^ xork) << 4;
            a0n = *(const v4i*)(As0 + cn);
            a1n = *(const v4i*)(As1 + cn);
        }
        acc00 = __builtin_amdgcn_mfma_i32_32x32x32_i8(a0c, b0c, acc00, 0, 0, 0);
        acc01 = __builtin_amdgcn_mfma_i32_32x32x32_i8(a0c, b1c, acc01, 0, 0, 0);
        acc10 = __builtin_amdgcn_mfma_i32_32x32x32_i8(a1c, b0c, acc10, 0, 0, 0);
        acc11 = __builtin_amdgcn_mfma_i32_32x32x32_i8(a1c, b1c, acc11, 0, 0, 0);
        b0c = b0n; b1c = b1n; a0c = a0n; a1c = a1n;
    }

    // ---- epilogue: C/D layout col=lane&31, row=(reg&3)+8*(reg>>2)+4*sel ----
    int n_lane = lane & 31;
    int rquad = 4 * sel;
    v16i accs[2][2] = {{acc00, acc01}, {acc10, acc11}};
    #pragma unroll
    for (int i = 0; i < 2; i++) {
        int mloc = i * 32;
        #pragma unroll
        for (int j = 0; j < 2; j++) {
            int n = wn + j * 32 + n_lane;
            float wsn = wscale[n];
            float bn = bias[n];
            v16i A = accs[i][j];
            #pragma unroll
            for (int r = 0; r < 16; r++) {
                int ml = mloc + (r & 3) + 8 * (r >> 2) + rquad;
                __builtin_nontemporal_store(
                    (float)A[r] * xs_lds[ml] * wsn + bn,
                    &out[(size_t)(m0 + ml) * N + n]);
            }
        }
    }
}

extern "C" void kernel_launch(void* const* d_in, const int* in_sizes, int n_in,
                              void* d_out, int out_size, void* d_ws, size_t ws_size,
                              hipStream_t stream)
{
    const float* x    = (const float*)d_in[0];
    const float* w    = (const float*)d_in[1];
    const float* bias = (const float*)d_in[2];
    float* out = (float*)d_out;

    int DOUT = in_sizes[2];        // 1024
    int M = in_sizes[0] / DIN;     // 32768

    char* ws  = (char*)d_ws;
    char* wq  = ws;
    float* wsc = (float*)(wq + (size_t)DOUT * DIN);

    quant_w<<<DOUT / 4, 256, 0, stream>>>(w, wq, wsc);
    gemm_i8_fused<<<M / 64, 1024, 0, stream>>>(x, wq, wsc, bias, out, DOUT);
}